// Round 9
// baseline (322.010 us; speedup 1.0000x reference)
//
#include <hip/hip_runtime.h>
#include <math.h>

#define DIM 512
#define NHEAD 8
#define HD 64
#define FFN_DIM 2048
#define BATCH 4
#define SEQ 2048
#define MTOK (BATCH*SEQ)   // 8192

typedef __attribute__((ext_vector_type(8))) short bf16x8;
typedef __attribute__((ext_vector_type(4))) float f32x4;

__device__ __forceinline__ unsigned short f2b(float f){
    unsigned int u = __float_as_uint(f);
    u += 0x7fffu + ((u >> 16) & 1u);
    return (unsigned short)(u >> 16);
}
__device__ __forceinline__ float b2f(unsigned short u){
    return __uint_as_float(((unsigned int)u) << 16);
}
// pack two floats -> two bf16 (truncation), 1 v_perm_b32
__device__ __forceinline__ unsigned int pack_trunc(float f0, float f1){
    return __builtin_amdgcn_perm(__float_as_uint(f1), __float_as_uint(f0), 0x07060302u);
}
// async 16B global->LDS. lds must be wave-uniform; dest = lds + lane*16.
__device__ __forceinline__ void async_cp16(const unsigned short* g, unsigned short* l){
    __builtin_amdgcn_global_load_lds((const __attribute__((address_space(1))) unsigned int*)g,
                                     (__attribute__((address_space(3))) unsigned int*)l, 16, 0, 0);
}

// ---------- fused prep: x->bf16, all weight transposes, bias pack ----------
__device__ __forceinline__ void transp32(const float* __restrict__ in, unsigned short* __restrict__ out,
                                         int N, int K, int n0_rd, int n0_wr, int k0,
                                         unsigned short (&t)[32][33], int tid){
    int tx = tid & 31, ty = tid >> 5;   // 32 x 8
    #pragma unroll
    for (int u = 0; u < 4; u++)
        t[tx][ty + 8*u] = f2b(in[(size_t)(k0 + ty + 8*u)*N + n0_rd + tx]);
    __syncthreads();
    #pragma unroll
    for (int u = 0; u < 4; u++)
        out[(size_t)(n0_wr + ty + 8*u)*K + k0 + tx] = t[ty + 8*u][tx];
}

__global__ void prep_kernel(const float* __restrict__ x,
                            const float* __restrict__ wq, const float* __restrict__ wk,
                            const float* __restrict__ wv, const float* __restrict__ wo,
                            const float* __restrict__ w1, const float* __restrict__ w2,
                            const float* __restrict__ bq, const float* __restrict__ bk,
                            const float* __restrict__ bv,
                            unsigned short* __restrict__ xb, unsigned short* __restrict__ wqkvT,
                            unsigned short* __restrict__ woT, unsigned short* __restrict__ w1T,
                            unsigned short* __restrict__ w2T, float* __restrict__ bqkv)
{
    __shared__ unsigned short t[32][33];
    int bid = blockIdx.x, tid = threadIdx.x;
    if (bid < 4096) {
        int i = (bid*256 + tid)*4;
        float4 v = *(const float4*)(x + i);
        ushort4 o; o.x=f2b(v.x); o.y=f2b(v.y); o.z=f2b(v.z); o.w=f2b(v.w);
        *(ushort4*)(xb + i) = o;
    } else if (bid < 4864) {                       // wqkv pack+transpose
        int r = bid - 4096;
        int n0 = (r % 48)*32, k0 = (r / 48)*32;
        const float* w = (n0 < 512) ? wq : (n0 < 1024) ? wk : wv;
        transp32(w, wqkvT, 512, 512, n0 & 511, n0, k0, t, tid);
    } else if (bid < 5120) {                       // wo
        int r = bid - 4864;
        int n0 = (r % 16)*32, k0 = (r / 16)*32;
        transp32(wo, woT, 512, 512, n0, n0, k0, t, tid);
    } else if (bid < 6144) {                       // w1 [512][2048] -> [2048][512]
        int r = bid - 5120;
        int n0 = (r % 64)*32, k0 = (r / 64)*32;
        transp32(w1, w1T, 2048, 512, n0, n0, k0, t, tid);
    } else if (bid < 7168) {                       // w2 [2048][512] -> [512][2048]
        int r = bid - 6144;
        int n0 = (r % 16)*32, k0 = (r / 16)*32;
        transp32(w2, w2T, 512, 2048, n0, n0, k0, t, tid);
    } else {                                       // bias pack
        int i = (bid - 7168)*256 + tid;
        if (i < 1536)
            bqkv[i] = (i < 512) ? bq[i] : (i < 1024) ? bk[i-512] : bv[i-1024];
    }
}

// ---------- MFMA GEMM: C[M][N] = A[M][K] @ Bt[N][K]^T + bias ----------
// Tiles: TMxTN in {128x128, 128x256, 256x128}. 4 waves/block.
// MODE 0: bf16 out.  MODE 1: QKV scatter (q pre-scaled by 0.125*log2e, v transposed).  MODE 2: GELU -> bf16.
// SK: split-K (blockIdx.z = K-slice; z>0 writes partial w/o bias at Cb + z*M*N).
template<int MODE, int TM, int TN, int SK>
__global__ __launch_bounds__(256)
void gemm_bf16(const unsigned short* __restrict__ A, const unsigned short* __restrict__ Bt,
               const float* __restrict__ bias,
               unsigned short* __restrict__ Cb,
               unsigned short* __restrict__ qo, unsigned short* __restrict__ ko,
               unsigned short* __restrict__ vTo,
               int M, int N, int K)
{
    constexpr int JN = (TM == 256 || TN == 256) ? 8 : 4;
    __shared__ unsigned short As[TM*64];
    __shared__ unsigned short Bs[TN*64];
    int tid  = threadIdx.x;
    int lane = tid & 63;
    int ln = lane & 15, qd = lane >> 4;
    int m0 = blockIdx.x * TM, n0 = blockIdx.y * TN;
    int wid = tid >> 6;
    int wm, wn;
    if (TM == 256)      { wm = wid*64;        wn = 0; }
    else if (TN == 256) { wm = (wid >> 1)*64; wn = (wid & 1)*128; }
    else                { wm = (wid >> 1)*64; wn = (wid & 1)*64; }
    int kbeg = (SK > 1) ? (int)blockIdx.z * (K/SK) : 0;
    int kend = kbeg + K/SK;
    if (SK > 1 && MODE == 0) Cb += (size_t)blockIdx.z * M * N;

    f32x4 acc[4][JN];
    #pragma unroll
    for (int i = 0; i < 4; i++)
        #pragma unroll
        for (int j = 0; j < JN; j++) acc[i][j] = (f32x4){0.f,0.f,0.f,0.f};

    for (int k0 = kbeg; k0 < kend; k0 += 64) {
        #pragma unroll
        for (int i = 0; i < TM/32; i++) {
            int cid = i*256 + tid;
            int row = cid >> 3, cs = cid & 7;
            int cg = cs ^ (row & 7);
            async_cp16(&A[(size_t)(m0+row)*K + k0 + cg*8], &As[(cid & ~63) * 8]);
        }
        #pragma unroll
        for (int i = 0; i < TN/32; i++) {
            int cid = i*256 + tid;
            int row = cid >> 3, cs = cid & 7;
            int cg = cs ^ (row & 7);
            async_cp16(&Bt[(size_t)(n0+row)*K + k0 + cg*8], &Bs[(cid & ~63) * 8]);
        }
        __syncthreads();
        #pragma unroll
        for (int kk = 0; kk < 64; kk += 32) {
            int c0 = kk >> 3;
            bf16x8 af[4], bf[JN];
            #pragma unroll
            for (int t = 0; t < 4; t++)
                af[t] = *(bf16x8*)&As[(wm + t*16 + ln)*64 + ((c0 + qd) ^ (ln & 7))*8];
            #pragma unroll
            for (int t = 0; t < JN; t++)
                bf[t] = *(bf16x8*)&Bs[(wn + t*16 + ln)*64 + ((c0 + qd) ^ (ln & 7))*8];
            #pragma unroll
            for (int i = 0; i < 4; i++)
                #pragma unroll
                for (int j = 0; j < JN; j++)
                    acc[i][j] = __builtin_amdgcn_mfma_f32_16x16x32_bf16(af[i], bf[j], acc[i][j], 0,0,0);
        }
        __syncthreads();
    }

    const float QSCALE = 0.18033688011112042f;   // 0.125 * log2(e)
    #pragma unroll
    for (int i = 0; i < 4; i++) {
        int mb = m0 + wm + i*16 + qd*4;
        #pragma unroll
        for (int j = 0; j < JN; j++) {
            int c = n0 + wn + j*16 + ln;
            float bv_ = (SK > 1 && blockIdx.z) ? 0.f : bias[c];
            float v[4];
            #pragma unroll
            for (int r = 0; r < 4; r++) v[r] = acc[i][j][r] + bv_;
            if (MODE == 0) {
                #pragma unroll
                for (int r = 0; r < 4; r++) Cb[(size_t)(mb+r)*N + c] = f2b(v[r]);
            } else if (MODE == 2) {
                #pragma unroll
                for (int r = 0; r < 4; r++) {
                    float g = 0.5f * v[r] * (1.0f + erff(v[r] * 0.70710678118654752f));
                    Cb[(size_t)(mb+r)*N + c] = f2b(g);
                }
            } else {
                int b = mb >> 11, t0 = mb & 2047;
                if (c < 512) {
                    int h = c >> 6, hd = c & 63;
                    #pragma unroll
                    for (int r = 0; r < 4; r++)
                        qo[(((size_t)(b*8 + h))*SEQ + t0 + r)*64 + hd] = f2b(v[r] * QSCALE);
                } else if (c < 1024) {
                    int cc = c - 512, h = cc >> 6, hd = cc & 63;
                    #pragma unroll
                    for (int r = 0; r < 4; r++)
                        ko[(((size_t)(b*8 + h))*SEQ + t0 + r)*64 + hd] = f2b(v[r]);
                } else {
                    int cc = c - 1024, h = cc >> 6, hd = cc & 63;
                    ushort4 pk;
                    pk.x = f2b(v[0]); pk.y = f2b(v[1]); pk.z = f2b(v[2]); pk.w = f2b(v[3]);
                    *(ushort4*)&vTo[(((size_t)(b*8 + h))*64 + hd)*SEQ + t0] = pk;
                }
            }
        }
    }
}

// ---------- MFMA flash attention (R7 winner: S^T, no-max softmax, 128 q/block, 4 waves) ----------
// LDS map (shorts): Ks0[0,4096) Vs0[4096,8192) Ks1[8192,12288) Vs1[12288,16384)
// Ps[16384,24576) (128x64). Qs (128x64) aliases Ks1+Vs1. Total 48 KB.
__global__ __launch_bounds__(256)
void attn_mfma(const unsigned short* __restrict__ Q, const unsigned short* __restrict__ K,
               const unsigned short* __restrict__ VT, unsigned short* __restrict__ O)
{
    __shared__ unsigned short lds[24576];
    unsigned short* Qs = lds + 8192;
    unsigned short* Ps = lds + 16384;
    int tid  = threadIdx.x;
    int wid  = tid >> 6, lane = tid & 63;
    int ln = lane & 15, qd = lane >> 4;
    int qb = blockIdx.x, bh = blockIdx.y;

    // prologue: stage Q (128x64) + K(0)/V(0)
    #pragma unroll
    for (int i = 0; i < 4; i++) {
        int cid = i*256 + tid;
        int row = cid >> 3, cs = cid & 7;
        int cg = cs ^ (row & 7);
        async_cp16(&Q[((size_t)bh*SEQ + qb*128 + row)*64 + cg*8], &Qs[(cid & ~63)*8]);
    }
    #pragma unroll
    for (int i = 0; i < 2; i++) {
        int cid = i*256 + tid;
        int row = cid >> 3, cs = cid & 7;
        int cg = cs ^ (row & 7);
        async_cp16(&K [((size_t)bh*SEQ + row)*64 + cg*8], &lds[(cid & ~63)*8]);
        async_cp16(&VT[((size_t)bh*64 + row)*SEQ + cg*8], &lds[4096 + (cid & ~63)*8]);
    }
    __syncthreads();   // all staging done

    // hoist kt-invariant Q fragments (2 q-subtiles x 2 K-chunks), then free Qs
    bf16x8 qf[2][2];
    #pragma unroll
    for (int qs = 0; qs < 2; qs++)
        #pragma unroll
        for (int kk = 0; kk < 2; kk++)
            qf[qs][kk] = *(bf16x8*)&Qs[(wid*32 + qs*16 + ln)*64 + ((kk*4 + qd) ^ (ln & 7))*8];
    __syncthreads();   // Qs readers done before kt=0 prefetch into buf1

    f32x4 o[2][4];
    #pragma unroll
    for (int qs = 0; qs < 2; qs++)
        #pragma unroll
        for (int dt = 0; dt < 4; dt++) o[qs][dt] = (f32x4){0.f,0.f,0.f,0.f};
    float l_i[2] = {0.f, 0.f};

    for (int kt = 0; kt < 32; kt++) {
        int kof = (kt & 1) * 8192;
        int vof = 4096 + kof;
        if (kt < 31) {
            int nkof = 8192 - kof;
            #pragma unroll
            for (int i = 0; i < 2; i++) {
                int cid = i*256 + tid;
                int row = cid >> 3, cs = cid & 7;
                int cg = cs ^ (row & 7);
                async_cp16(&K [((size_t)bh*SEQ + (kt+1)*64 + row)*64 + cg*8], &lds[nkof + (cid & ~63)*8]);
                async_cp16(&VT[((size_t)bh*64 + row)*SEQ + (kt+1)*64 + cg*8], &lds[nkof + 4096 + (cid & ~63)*8]);
            }
        }

        // S^T: 64 keys x 32 q (2 subtiles); kf reused across both subtiles
        f32x4 s[2][4];
        #pragma unroll
        for (int qs = 0; qs < 2; qs++)
            #pragma unroll
            for (int nt = 0; nt < 4; nt++) s[qs][nt] = (f32x4){0.f,0.f,0.f,0.f};
        #pragma unroll
        for (int kk = 0; kk < 2; kk++) {
            #pragma unroll
            for (int nt = 0; nt < 4; nt++) {
                bf16x8 kf = *(bf16x8*)&lds[kof + (nt*16 + ln)*64 + ((kk*4 + qd) ^ (ln & 7))*8];
                s[0][nt] = __builtin_amdgcn_mfma_f32_16x16x32_bf16(kf, qf[0][kk], s[0][nt], 0,0,0);
                s[1][nt] = __builtin_amdgcn_mfma_f32_16x16x32_bf16(kf, qf[1][kk], s[1][nt], 0,0,0);
            }
        }

        // exp2 + lane-local sums; P^T -> Ps (wave-private rows: no barrier)
        #pragma unroll
        for (int qs = 0; qs < 2; qs++) {
            #pragma unroll
            for (int nt = 0; nt < 4; nt++) {
                #pragma unroll
                for (int r = 0; r < 4; r++) {
                    float p = __builtin_amdgcn_exp2f(s[qs][nt][r]);
                    s[qs][nt][r] = p;
                    l_i[qs] += p;
                }
                uint2 pk;
                pk.x = pack_trunc(s[qs][nt][0], s[qs][nt][1]);
                pk.y = pack_trunc(s[qs][nt][2], s[qs][nt][3]);
                *(uint2*)&Ps[(wid*32 + qs*16 + ln)*64 + ((nt*2 + (qd>>1)) ^ (ln & 7))*8 + (qd&1)*4] = pk;
            }
        }

        // O^T += V^T @ P^T ; vf reused across both q-subtiles
        #pragma unroll
        for (int kk = 0; kk < 2; kk++) {
            bf16x8 pf0 = *(bf16x8*)&Ps[(wid*32 + ln)*64      + ((kk*4 + qd) ^ (ln & 7))*8];
            bf16x8 pf1 = *(bf16x8*)&Ps[(wid*32 + 16 + ln)*64 + ((kk*4 + qd) ^ (ln & 7))*8];
            #pragma unroll
            for (int dt = 0; dt < 4; dt++) {
                bf16x8 vf = *(bf16x8*)&lds[vof + (dt*16 + ln)*64 + ((kk*4 + qd) ^ (ln & 7))*8];
                o[0][dt] = __builtin_amdgcn_mfma_f32_16x16x32_bf16(vf, pf0, o[0][dt], 0,0,0);
                o[1][dt] = __builtin_amdgcn_mfma_f32_16x16x32_bf16(vf, pf1, o[1][dt], 0,0,0);
            }
        }
        __syncthreads();   // prefetch drained + all readers of current buffers done
    }

    int b = bh >> 3, h = bh & 7;
    #pragma unroll
    for (int qs = 0; qs < 2; qs++) {
        float l = l_i[qs];
        l += __shfl_xor(l, 16);
        l += __shfl_xor(l, 32);
        float linv = 1.0f / l;
        int t = qb*128 + wid*32 + qs*16 + ln;
        #pragma unroll
        for (int dt = 0; dt < 4; dt++) {
            ushort4 pk;
            pk.x = f2b(o[qs][dt][0]*linv); pk.y = f2b(o[qs][dt][1]*linv);
            pk.z = f2b(o[qs][dt][2]*linv); pk.w = f2b(o[qs][dt][3]*linv);
            *(ushort4*)&O[((size_t)b*SEQ + t)*DIM + h*64 + dt*16 + qd*4] = pk;
        }
    }
}

// ---------- LN(m0b + m1b + res_fp32) -> bf16 (wave-per-row; 2 bf16 partials) ----------
__global__ void ln1_kernel(const unsigned short* __restrict__ m0b, const unsigned short* __restrict__ m1b,
                           const float* __restrict__ resp,
                           const float* __restrict__ g, const float* __restrict__ be,
                           unsigned short* __restrict__ outb)
{
    int row  = blockIdx.x*4 + (threadIdx.x >> 6);
    int lane = threadIdx.x & 63;
    size_t base = (size_t)row * DIM + lane*8;

    ushort4 a0 = *(const ushort4*)(m0b + base);
    ushort4 a1 = *(const ushort4*)(m0b + base + 4);
    ushort4 c0 = *(const ushort4*)(m1b + base);
    ushort4 c1 = *(const ushort4*)(m1b + base + 4);
    float4 r0 = *(const float4*)(resp + base);
    float4 r1 = *(const float4*)(resp + base + 4);
    float v[8] = { b2f(a0.x)+b2f(c0.x)+r0.x, b2f(a0.y)+b2f(c0.y)+r0.y,
                   b2f(a0.z)+b2f(c0.z)+r0.z, b2f(a0.w)+b2f(c0.w)+r0.w,
                   b2f(a1.x)+b2f(c1.x)+r1.x, b2f(a1.y)+b2f(c1.y)+r1.y,
                   b2f(a1.z)+b2f(c1.z)+r1.z, b2f(a1.w)+b2f(c1.w)+r1.w };
    float s = 0.f, s2 = 0.f;
    #pragma unroll
    for (int i = 0; i < 8; i++) { s += v[i]; s2 += v[i]*v[i]; }
    #pragma unroll
    for (int d = 32; d >= 1; d >>= 1) { s += __shfl_xor(s, d); s2 += __shfl_xor(s2, d); }
    float mean = s * (1.0f / DIM);
    float rstd = rsqrtf(s2 * (1.0f / DIM) - mean*mean + 1e-5f);

    float4 g0 = *(const float4*)(g + lane*8);
    float4 g1 = *(const float4*)(g + lane*8 + 4);
    float4 b0 = *(const float4*)(be + lane*8);
    float4 b1 = *(const float4*)(be + lane*8 + 4);
    float gg[8] = {g0.x,g0.y,g0.z,g0.w,g1.x,g1.y,g1.z,g1.w};
    float bb[8] = {b0.x,b0.y,b0.z,b0.w,b1.x,b1.y,b1.z,b1.w};
    float o[8];
    #pragma unroll
    for (int i = 0; i < 8; i++) o[i] = (v[i]-mean)*rstd*gg[i] + bb[i];
    ushort4 p0, p1;
    p0.x=f2b(o[0]); p0.y=f2b(o[1]); p0.z=f2b(o[2]); p0.w=f2b(o[3]);
    p1.x=f2b(o[4]); p1.y=f2b(o[5]); p1.z=f2b(o[6]); p1.w=f2b(o[7]);
    *(ushort4*)(outb + base)     = p0;
    *(ushort4*)(outb + base + 4) = p1;
}

// ---------- LN(4 bf16 partials + res_bf16) -> fp32 ----------
__global__ void ln2_kernel(const unsigned short* __restrict__ mb,
                           const unsigned short* __restrict__ resb,
                           const float* __restrict__ g, const float* __restrict__ be,
                           float* __restrict__ outf)
{
    int row  = blockIdx.x*4 + (threadIdx.x >> 6);
    int lane = threadIdx.x & 63;
    size_t base = (size_t)row * DIM + lane*8;
    const size_t PSTRIDE = (size_t)MTOK * DIM;

    float v[8];
    {
        ushort4 rb0 = *(const ushort4*)(resb + base);
        ushort4 rb1 = *(const ushort4*)(resb + base + 4);
        v[0]=b2f(rb0.x); v[1]=b2f(rb0.y); v[2]=b2f(rb0.z); v[3]=b2f(rb0.w);
        v[4]=b2f(rb1.x); v[5]=b2f(rb1.y); v[6]=b2f(rb1.z); v[7]=b2f(rb1.w);
    }
    #pragma unroll
    for (int p = 0; p < 4; p++) {
        ushort4 a0 = *(const ushort4*)(mb + p*PSTRIDE + base);
        ushort4 a1 = *(const ushort4*)(mb + p*PSTRIDE + base + 4);
        v[0]+=b2f(a0.x); v[1]+=b2f(a0.y); v[2]+=b2f(a0.z); v[3]+=b2f(a0.w);
        v[4]+=b2f(a1.x); v[5]+=b2f(a1.y); v[6]+=b2f(a1.z); v[7]+=b2f(a1.w);
    }
    float s = 0.f, s2 = 0.f;
    #pragma unroll
    for (int i = 0; i < 8; i++) { s += v[i]; s2 += v[i]*v[i]; }
    #pragma unroll
    for (int d = 32; d >= 1; d >>= 1) { s += __shfl_xor(s, d); s2 += __shfl_xor(s2, d); }
    float mean = s * (1.0f / DIM);
    float rstd = rsqrtf(s2 * (1.0f / DIM) - mean*mean + 1e-5f);

    float4 g0 = *(const float4*)(g + lane*8);
    float4 g1 = *(const float4*)(g + lane*8 + 4);
    float4 b0 = *(const float4*)(be + lane*8);
    float4 b1 = *(const float4*)(be + lane*8 + 4);
    float gg[8] = {g0.x,g0.y,g0.z,g0.w,g1.x,g1.y,g1.z,g1.w};
    float bb[8] = {b0.x,b0.y,b0.z,b0.w,b1.x,b1.y,b1.z,b1.w};
    float o[8];
    #pragma unroll
    for (int i = 0; i < 8; i++) o[i] = (v[i] - mean)*rstd*gg[i] + bb[i];
    *(float4*)(outf + base)     = (float4){o[0],o[1],o[2],o[3]};
    *(float4*)(outf + base + 4) = (float4){o[4],o[5],o[6],o[7]};
}

extern "C" void kernel_launch(void* const* d_in, const int* in_sizes, int n_in,
                              void* d_out, int out_size, void* d_ws, size_t ws_size,
                              hipStream_t stream) {
    const float* x   = (const float*)d_in[0];
    const float* wq  = (const float*)d_in[1];
    const float* bq  = (const float*)d_in[2];
    const float* wk  = (const float*)d_in[3];
    const float* bk  = (const float*)d_in[4];
    const float* wv  = (const float*)d_in[5];
    const float* bv  = (const float*)d_in[6];
    const float* wo  = (const float*)d_in[7];
    const float* bo  = (const float*)d_in[8];
    const float* w1  = (const float*)d_in[9];
    const float* b1  = (const float*)d_in[10];
    const float* w2  = (const float*)d_in[11];
    const float* b2  = (const float*)d_in[12];
    const float* g1  = (const float*)d_in[13];
    const float* be1 = (const float*)d_in[14];
    const float* g2  = (const float*)d_in[15];
    const float* be2 = (const float*)d_in[16];
    float* out = (float*)d_out;

    char* w = (char*)d_ws;
    size_t off = 0;
    auto alloc = [&](size_t bytes){ void* p = w + off; off += (bytes + 255) & ~(size_t)255; return p; };
    unsigned short* xb     = (unsigned short*)alloc((size_t)MTOK*DIM*2);
    unsigned short* wqkvT  = (unsigned short*)alloc((size_t)1536*512*2);
    unsigned short* woT    = (unsigned short*)alloc((size_t)512*512*2);
    unsigned short* w1T    = (unsigned short*)alloc((size_t)2048*512*2);
    unsigned short* w2T    = (unsigned short*)alloc((size_t)512*2048*2);
    float*          bqkv   = (float*)alloc(1536*4);
    unsigned short* qb_    = (unsigned short*)alloc((size_t)32*SEQ*64*2);
    unsigned short* kb_    = (unsigned short*)alloc((size_t)32*SEQ*64*2);
    unsigned short* vT_    = (unsigned short*)alloc((size_t)32*64*SEQ*2);
    unsigned short* attno  = (unsigned short*)alloc((size_t)MTOK*DIM*2);
    unsigned short* x1b    = (unsigned short*)alloc((size_t)MTOK*DIM*2);
    unsigned short* h_     = (unsigned short*)alloc((size_t)MTOK*FFN_DIM*2);
    unsigned short* ffb    = (unsigned short*)alloc((size_t)4*MTOK*DIM*2);   // bf16 split-K partials (up to 4)

    // fused prep (1 launch): cvt_x | wqkv | wo | w1 | w2 | bias
    prep_kernel<<<7174, 256, 0, stream>>>(x, wq, wk, wv, wo, w1, w2, bq, bk, bv,
                                          xb, wqkvT, woT, w1T, w2T, bqkv);

    // QKV (fused): [8192,512] x [512,1536], 128x128
    gemm_bf16<1,128,128,1><<<dim3(64,12), 256, 0, stream>>>(xb, wqkvT, bqkv, nullptr,
                                                            qb_, kb_, vT_, MTOK, 1536, DIM);
    // attention (R7 config: 128 q/block, 4 waves)
    attn_mfma<<<dim3(16,32), 256, 0, stream>>>(qb_, kb_, vT_, attno);
    // O-proj -> 2 bf16 partials (128x128, split-K=2)
    gemm_bf16<0,128,128,2><<<dim3(64,4,2), 256, 0, stream>>>(attno, woT, bo, ffb,
                                                             nullptr, nullptr, nullptr, MTOK, DIM, DIM);
    // LN1(ff0+ff1+x) -> bf16
    ln1_kernel<<<MTOK/4, 256, 0, stream>>>(ffb, ffb + (size_t)MTOK*DIM, x, g1, be1, x1b);
    // FFN1 + GELU -> bf16 h (128x256 tile: 64 MFMA / 24 ds_read per k-iter)
    gemm_bf16<2,128,256,1><<<dim3(64,8), 256, 0, stream>>>(x1b, w1T, b1, h_,
                                                           nullptr, nullptr, nullptr, MTOK, FFN_DIM, DIM);
    // FFN2 -> 4 bf16 partials (256x128 tile, split-K=4)
    gemm_bf16<0,256,128,4><<<dim3(32,4,4), 256, 0, stream>>>(h_, w2T, b2, ffb,
                                                             nullptr, nullptr, nullptr, MTOK, DIM, FFN_DIM);
    // LN2(4 partials + x1b) -> out (fp32)
    ln2_kernel<<<MTOK/4, 256, 0, stream>>>(ffb, x1b, g2, be2, out);
}

// Round 10
// 249.999 us; speedup vs baseline: 1.2880x; 1.2880x over previous
//
#include <hip/hip_runtime.h>
#include <math.h>

#define DIM 512
#define NHEAD 8
#define HD 64
#define FFN_DIM 2048
#define BATCH 4
#define SEQ 2048
#define MTOK (BATCH*SEQ)   // 8192

typedef __attribute__((ext_vector_type(8))) short bf16x8;
typedef __attribute__((ext_vector_type(4))) float f32x4;

__device__ __forceinline__ unsigned short f2b(float f){
    unsigned int u = __float_as_uint(f);
    u += 0x7fffu + ((u >> 16) & 1u);
    return (unsigned short)(u >> 16);
}
__device__ __forceinline__ float b2f(unsigned short u){
    return __uint_as_float(((unsigned int)u) << 16);
}
// pack two floats -> two bf16 (truncation), 1 v_perm_b32
__device__ __forceinline__ unsigned int pack_trunc(float f0, float f1){
    return __builtin_amdgcn_perm(__float_as_uint(f1), __float_as_uint(f0), 0x07060302u);
}
// async 16B global->LDS. lds must be wave-uniform; dest = lds + lane*16.
__device__ __forceinline__ void async_cp16(const unsigned short* g, unsigned short* l){
    __builtin_amdgcn_global_load_lds((const __attribute__((address_space(1))) unsigned int*)g,
                                     (__attribute__((address_space(3))) unsigned int*)l, 16, 0, 0);
}
// tanh-form GELU via exp2 (~10 VALU ops; |err vs exact erf-GELU| <= ~3e-3)
__device__ __forceinline__ float gelu_fast(float x){
    float x3 = x*x*x;
    float y  = 2.302588f * (x + 0.044715f*x3);   // 2*log2(e)*sqrt(2/pi)*(x+0.044715x^3)
    float t  = __builtin_amdgcn_exp2f(y);
    // 0.5x(1+tanh) = x * t/(t+1)
    return x * t * __builtin_amdgcn_rcpf(t + 1.0f);
}

// ---------- fused prep: x->bf16, all weight transposes, bias pack ----------
__device__ __forceinline__ void transp32(const float* __restrict__ in, unsigned short* __restrict__ out,
                                         int N, int K, int n0_rd, int n0_wr, int k0,
                                         unsigned short (&t)[32][33], int tid){
    int tx = tid & 31, ty = tid >> 5;   // 32 x 8
    #pragma unroll
    for (int u = 0; u < 4; u++)
        t[tx][ty + 8*u] = f2b(in[(size_t)(k0 + ty + 8*u)*N + n0_rd + tx]);
    __syncthreads();
    #pragma unroll
    for (int u = 0; u < 4; u++)
        out[(size_t)(n0_wr + ty + 8*u)*K + k0 + tx] = t[ty + 8*u][tx];
}

__global__ void prep_kernel(const float* __restrict__ x,
                            const float* __restrict__ wq, const float* __restrict__ wk,
                            const float* __restrict__ wv, const float* __restrict__ wo,
                            const float* __restrict__ w1, const float* __restrict__ w2,
                            const float* __restrict__ bq, const float* __restrict__ bk,
                            const float* __restrict__ bv,
                            unsigned short* __restrict__ xb, unsigned short* __restrict__ wqkvT,
                            unsigned short* __restrict__ woT, unsigned short* __restrict__ w1T,
                            unsigned short* __restrict__ w2T, float* __restrict__ bqkv)
{
    __shared__ unsigned short t[32][33];
    int bid = blockIdx.x, tid = threadIdx.x;
    if (bid < 4096) {
        int i = (bid*256 + tid)*4;
        float4 v = *(const float4*)(x + i);
        ushort4 o; o.x=f2b(v.x); o.y=f2b(v.y); o.z=f2b(v.z); o.w=f2b(v.w);
        *(ushort4*)(xb + i) = o;
    } else if (bid < 4864) {                       // wqkv pack+transpose
        int r = bid - 4096;
        int n0 = (r % 48)*32, k0 = (r / 48)*32;
        const float* w = (n0 < 512) ? wq : (n0 < 1024) ? wk : wv;
        transp32(w, wqkvT, 512, 512, n0 & 511, n0, k0, t, tid);
    } else if (bid < 5120) {                       // wo
        int r = bid - 4864;
        int n0 = (r % 16)*32, k0 = (r / 16)*32;
        transp32(wo, woT, 512, 512, n0, n0, k0, t, tid);
    } else if (bid < 6144) {                       // w1 [512][2048] -> [2048][512]
        int r = bid - 5120;
        int n0 = (r % 64)*32, k0 = (r / 64)*32;
        transp32(w1, w1T, 2048, 512, n0, n0, k0, t, tid);
    } else if (bid < 7168) {                       // w2 [2048][512] -> [512][2048]
        int r = bid - 6144;
        int n0 = (r % 16)*32, k0 = (r / 16)*32;
        transp32(w2, w2T, 512, 2048, n0, n0, k0, t, tid);
    } else {                                       // bias pack
        int i = (bid - 7168)*256 + tid;
        if (i < 1536)
            bqkv[i] = (i < 512) ? bq[i] : (i < 1024) ? bk[i-512] : bv[i-1024];
    }
}

// ---------- MFMA GEMM: C[M][N] = A[M][K] @ Bt[N][K]^T + bias ----------
// 128x128 tile, 4 waves. __launch_bounds__(256,4): cap VGPR<=128 -> 4 blocks/CU
// (barrier-drain hiding needs >=3-4 co-resident blocks; R9 showed 2/CU stalls 62%).
// MODE 0: bf16 out.  MODE 1: QKV scatter (q pre-scaled by 0.125*log2e, v transposed).  MODE 2: GELU -> bf16.
// SK: split-K (blockIdx.z = K-slice; z>0 writes partial w/o bias at Cb + z*M*N).
template<int MODE, int SK>
__global__ __launch_bounds__(256, 4)
void gemm_bf16(const unsigned short* __restrict__ A, const unsigned short* __restrict__ Bt,
               const float* __restrict__ bias,
               unsigned short* __restrict__ Cb,
               unsigned short* __restrict__ qo, unsigned short* __restrict__ ko,
               unsigned short* __restrict__ vTo,
               int M, int N, int K)
{
    __shared__ unsigned short As[128*64];
    __shared__ unsigned short Bs[128*64];
    int tid  = threadIdx.x;
    int lane = tid & 63;
    int ln = lane & 15, qd = lane >> 4;
    int m0 = blockIdx.x * 128, n0 = blockIdx.y * 128;
    int wid = tid >> 6;
    int wm = (wid >> 1) * 64;
    int wn = (wid & 1) * 64;
    int kbeg = (SK > 1) ? (int)blockIdx.z * (K/SK) : 0;
    int kend = kbeg + K/SK;
    if (SK > 1 && MODE == 0) Cb += (size_t)blockIdx.z * M * N;

    f32x4 acc[4][4];
    #pragma unroll
    for (int i = 0; i < 4; i++)
        #pragma unroll
        for (int j = 0; j < 4; j++) acc[i][j] = (f32x4){0.f,0.f,0.f,0.f};

    for (int k0 = kbeg; k0 < kend; k0 += 64) {
        #pragma unroll
        for (int i = 0; i < 4; i++) {
            int cid = i*256 + tid;
            int row = cid >> 3, cs = cid & 7;
            int cg = cs ^ (row & 7);
            async_cp16(&A[(size_t)(m0+row)*K + k0 + cg*8], &As[(cid & ~63) * 8]);
        }
        #pragma unroll
        for (int i = 0; i < 4; i++) {
            int cid = i*256 + tid;
            int row = cid >> 3, cs = cid & 7;
            int cg = cs ^ (row & 7);
            async_cp16(&Bt[(size_t)(n0+row)*K + k0 + cg*8], &Bs[(cid & ~63) * 8]);
        }
        __syncthreads();
        #pragma unroll
        for (int kk = 0; kk < 64; kk += 32) {
            int c0 = kk >> 3;
            bf16x8 af[4], bf[4];
            #pragma unroll
            for (int t = 0; t < 4; t++)
                af[t] = *(bf16x8*)&As[(wm + t*16 + ln)*64 + ((c0 + qd) ^ (ln & 7))*8];
            #pragma unroll
            for (int t = 0; t < 4; t++)
                bf[t] = *(bf16x8*)&Bs[(wn + t*16 + ln)*64 + ((c0 + qd) ^ (ln & 7))*8];
            #pragma unroll
            for (int i = 0; i < 4; i++)
                #pragma unroll
                for (int j = 0; j < 4; j++)
                    acc[i][j] = __builtin_amdgcn_mfma_f32_16x16x32_bf16(af[i], bf[j], acc[i][j], 0,0,0);
        }
        __syncthreads();
    }

    const float QSCALE = 0.18033688011112042f;   // 0.125 * log2(e)
    #pragma unroll
    for (int i = 0; i < 4; i++) {
        int mb = m0 + wm + i*16 + qd*4;
        #pragma unroll
        for (int j = 0; j < 4; j++) {
            int c = n0 + wn + j*16 + ln;
            float bv_ = (SK > 1 && blockIdx.z) ? 0.f : bias[c];
            float v[4];
            #pragma unroll
            for (int r = 0; r < 4; r++) v[r] = acc[i][j][r] + bv_;
            if (MODE == 0) {
                #pragma unroll
                for (int r = 0; r < 4; r++) Cb[(size_t)(mb+r)*N + c] = f2b(v[r]);
            } else if (MODE == 2) {
                #pragma unroll
                for (int r = 0; r < 4; r++)
                    Cb[(size_t)(mb+r)*N + c] = f2b(gelu_fast(v[r]));
            } else {
                int b = mb >> 11, t0 = mb & 2047;
                if (c < 512) {
                    int h = c >> 6, hd = c & 63;
                    #pragma unroll
                    for (int r = 0; r < 4; r++)
                        qo[(((size_t)(b*8 + h))*SEQ + t0 + r)*64 + hd] = f2b(v[r] * QSCALE);
                } else if (c < 1024) {
                    int cc = c - 512, h = cc >> 6, hd = cc & 63;
                    #pragma unroll
                    for (int r = 0; r < 4; r++)
                        ko[(((size_t)(b*8 + h))*SEQ + t0 + r)*64 + hd] = f2b(v[r]);
                } else {
                    int cc = c - 1024, h = cc >> 6, hd = cc & 63;
                    ushort4 pk;
                    pk.x = f2b(v[0]); pk.y = f2b(v[1]); pk.z = f2b(v[2]); pk.w = f2b(v[3]);
                    *(ushort4*)&vTo[(((size_t)(b*8 + h))*64 + hd)*SEQ + t0] = pk;
                }
            }
        }
    }
}

// ---------- MFMA flash attention (R7 winner: S^T, no-max softmax, 128 q/block, 4 waves) ----------
// LDS map (shorts): Ks0[0,4096) Vs0[4096,8192) Ks1[8192,12288) Vs1[12288,16384)
// Ps[16384,24576) (128x64). Qs (128x64) aliases Ks1+Vs1. Total 48 KB.
__global__ __launch_bounds__(256)
void attn_mfma(const unsigned short* __restrict__ Q, const unsigned short* __restrict__ K,
               const unsigned short* __restrict__ VT, unsigned short* __restrict__ O)
{
    __shared__ unsigned short lds[24576];
    unsigned short* Qs = lds + 8192;
    unsigned short* Ps = lds + 16384;
    int tid  = threadIdx.x;
    int wid  = tid >> 6, lane = tid & 63;
    int ln = lane & 15, qd = lane >> 4;
    int qb = blockIdx.x, bh = blockIdx.y;

    // prologue: stage Q (128x64) + K(0)/V(0)
    #pragma unroll
    for (int i = 0; i < 4; i++) {
        int cid = i*256 + tid;
        int row = cid >> 3, cs = cid & 7;
        int cg = cs ^ (row & 7);
        async_cp16(&Q[((size_t)bh*SEQ + qb*128 + row)*64 + cg*8], &Qs[(cid & ~63)*8]);
    }
    #pragma unroll
    for (int i = 0; i < 2; i++) {
        int cid = i*256 + tid;
        int row = cid >> 3, cs = cid & 7;
        int cg = cs ^ (row & 7);
        async_cp16(&K [((size_t)bh*SEQ + row)*64 + cg*8], &lds[(cid & ~63)*8]);
        async_cp16(&VT[((size_t)bh*64 + row)*SEQ + cg*8], &lds[4096 + (cid & ~63)*8]);
    }
    __syncthreads();   // all staging done

    // hoist kt-invariant Q fragments (2 q-subtiles x 2 K-chunks), then free Qs
    bf16x8 qf[2][2];
    #pragma unroll
    for (int qs = 0; qs < 2; qs++)
        #pragma unroll
        for (int kk = 0; kk < 2; kk++)
            qf[qs][kk] = *(bf16x8*)&Qs[(wid*32 + qs*16 + ln)*64 + ((kk*4 + qd) ^ (ln & 7))*8];
    __syncthreads();   // Qs readers done before kt=0 prefetch into buf1

    f32x4 o[2][4];
    #pragma unroll
    for (int qs = 0; qs < 2; qs++)
        #pragma unroll
        for (int dt = 0; dt < 4; dt++) o[qs][dt] = (f32x4){0.f,0.f,0.f,0.f};
    float l_i[2] = {0.f, 0.f};

    for (int kt = 0; kt < 32; kt++) {
        int kof = (kt & 1) * 8192;
        int vof = 4096 + kof;
        if (kt < 31) {
            int nkof = 8192 - kof;
            #pragma unroll
            for (int i = 0; i < 2; i++) {
                int cid = i*256 + tid;
                int row = cid >> 3, cs = cid & 7;
                int cg = cs ^ (row & 7);
                async_cp16(&K [((size_t)bh*SEQ + (kt+1)*64 + row)*64 + cg*8], &lds[nkof + (cid & ~63)*8]);
                async_cp16(&VT[((size_t)bh*64 + row)*SEQ + (kt+1)*64 + cg*8], &lds[nkof + 4096 + (cid & ~63)*8]);
            }
        }

        // S^T: 64 keys x 32 q (2 subtiles); kf reused across both subtiles
        f32x4 s[2][4];
        #pragma unroll
        for (int qs = 0; qs < 2; qs++)
            #pragma unroll
            for (int nt = 0; nt < 4; nt++) s[qs][nt] = (f32x4){0.f,0.f,0.f,0.f};
        #pragma unroll
        for (int kk = 0; kk < 2; kk++) {
            #pragma unroll
            for (int nt = 0; nt < 4; nt++) {
                bf16x8 kf = *(bf16x8*)&lds[kof + (nt*16 + ln)*64 + ((kk*4 + qd) ^ (ln & 7))*8];
                s[0][nt] = __builtin_amdgcn_mfma_f32_16x16x32_bf16(kf, qf[0][kk], s[0][nt], 0,0,0);
                s[1][nt] = __builtin_amdgcn_mfma_f32_16x16x32_bf16(kf, qf[1][kk], s[1][nt], 0,0,0);
            }
        }

        // exp2 + lane-local sums; P^T -> Ps (wave-private rows: no barrier)
        #pragma unroll
        for (int qs = 0; qs < 2; qs++) {
            #pragma unroll
            for (int nt = 0; nt < 4; nt++) {
                #pragma unroll
                for (int r = 0; r < 4; r++) {
                    float p = __builtin_amdgcn_exp2f(s[qs][nt][r]);
                    s[qs][nt][r] = p;
                    l_i[qs] += p;
                }
                uint2 pk;
                pk.x = pack_trunc(s[qs][nt][0], s[qs][nt][1]);
                pk.y = pack_trunc(s[qs][nt][2], s[qs][nt][3]);
                *(uint2*)&Ps[(wid*32 + qs*16 + ln)*64 + ((nt*2 + (qd>>1)) ^ (ln & 7))*8 + (qd&1)*4] = pk;
            }
        }

        // O^T += V^T @ P^T ; vf reused across both q-subtiles
        #pragma unroll
        for (int kk = 0; kk < 2; kk++) {
            bf16x8 pf0 = *(bf16x8*)&Ps[(wid*32 + ln)*64      + ((kk*4 + qd) ^ (ln & 7))*8];
            bf16x8 pf1 = *(bf16x8*)&Ps[(wid*32 + 16 + ln)*64 + ((kk*4 + qd) ^ (ln & 7))*8];
            #pragma unroll
            for (int dt = 0; dt < 4; dt++) {
                bf16x8 vf = *(bf16x8*)&lds[vof + (dt*16 + ln)*64 + ((kk*4 + qd) ^ (ln & 7))*8];
                o[0][dt] = __builtin_amdgcn_mfma_f32_16x16x32_bf16(vf, pf0, o[0][dt], 0,0,0);
                o[1][dt] = __builtin_amdgcn_mfma_f32_16x16x32_bf16(vf, pf1, o[1][dt], 0,0,0);
            }
        }
        __syncthreads();   // prefetch drained + all readers of current buffers done
    }

    int b = bh >> 3, h = bh & 7;
    #pragma unroll
    for (int qs = 0; qs < 2; qs++) {
        float l = l_i[qs];
        l += __shfl_xor(l, 16);
        l += __shfl_xor(l, 32);
        float linv = 1.0f / l;
        int t = qb*128 + wid*32 + qs*16 + ln;
        #pragma unroll
        for (int dt = 0; dt < 4; dt++) {
            ushort4 pk;
            pk.x = f2b(o[qs][dt][0]*linv); pk.y = f2b(o[qs][dt][1]*linv);
            pk.z = f2b(o[qs][dt][2]*linv); pk.w = f2b(o[qs][dt][3]*linv);
            *(ushort4*)&O[((size_t)b*SEQ + t)*DIM + h*64 + dt*16 + qd*4] = pk;
        }
    }
}

// ---------- LN(m0b + m1b + res_fp32) -> bf16 (wave-per-row; 2 bf16 partials) ----------
__global__ void ln1_kernel(const unsigned short* __restrict__ m0b, const unsigned short* __restrict__ m1b,
                           const float* __restrict__ resp,
                           const float* __restrict__ g, const float* __restrict__ be,
                           unsigned short* __restrict__ outb)
{
    int row  = blockIdx.x*4 + (threadIdx.x >> 6);
    int lane = threadIdx.x & 63;
    size_t base = (size_t)row * DIM + lane*8;

    ushort4 a0 = *(const ushort4*)(m0b + base);
    ushort4 a1 = *(const ushort4*)(m0b + base + 4);
    ushort4 c0 = *(const ushort4*)(m1b + base);
    ushort4 c1 = *(const ushort4*)(m1b + base + 4);
    float4 r0 = *(const float4*)(resp + base);
    float4 r1 = *(const float4*)(resp + base + 4);
    float v[8] = { b2f(a0.x)+b2f(c0.x)+r0.x, b2f(a0.y)+b2f(c0.y)+r0.y,
                   b2f(a0.z)+b2f(c0.z)+r0.z, b2f(a0.w)+b2f(c0.w)+r0.w,
                   b2f(a1.x)+b2f(c1.x)+r1.x, b2f(a1.y)+b2f(c1.y)+r1.y,
                   b2f(a1.z)+b2f(c1.z)+r1.z, b2f(a1.w)+b2f(c1.w)+r1.w };
    float s = 0.f, s2 = 0.f;
    #pragma unroll
    for (int i = 0; i < 8; i++) { s += v[i]; s2 += v[i]*v[i]; }
    #pragma unroll
    for (int d = 32; d >= 1; d >>= 1) { s += __shfl_xor(s, d); s2 += __shfl_xor(s2, d); }
    float mean = s * (1.0f / DIM);
    float rstd = rsqrtf(s2 * (1.0f / DIM) - mean*mean + 1e-5f);

    float4 g0 = *(const float4*)(g + lane*8);
    float4 g1 = *(const float4*)(g + lane*8 + 4);
    float4 b0 = *(const float4*)(be + lane*8);
    float4 b1 = *(const float4*)(be + lane*8 + 4);
    float gg[8] = {g0.x,g0.y,g0.z,g0.w,g1.x,g1.y,g1.z,g1.w};
    float bb[8] = {b0.x,b0.y,b0.z,b0.w,b1.x,b1.y,b1.z,b1.w};
    float o[8];
    #pragma unroll
    for (int i = 0; i < 8; i++) o[i] = (v[i]-mean)*rstd*gg[i] + bb[i];
    ushort4 p0, p1;
    p0.x=f2b(o[0]); p0.y=f2b(o[1]); p0.z=f2b(o[2]); p0.w=f2b(o[3]);
    p1.x=f2b(o[4]); p1.y=f2b(o[5]); p1.z=f2b(o[6]); p1.w=f2b(o[7]);
    *(ushort4*)(outb + base)     = p0;
    *(ushort4*)(outb + base + 4) = p1;
}

// ---------- LN(m0b + m1b + res_bf16) -> fp32 ----------
__global__ void ln2_kernel(const unsigned short* __restrict__ m0b, const unsigned short* __restrict__ m1b,
                           const unsigned short* __restrict__ resb,
                           const float* __restrict__ g, const float* __restrict__ be,
                           float* __restrict__ outf)
{
    int row  = blockIdx.x*4 + (threadIdx.x >> 6);
    int lane = threadIdx.x & 63;
    size_t base = (size_t)row * DIM + lane*8;

    ushort4 a0 = *(const ushort4*)(m0b + base);
    ushort4 a1 = *(const ushort4*)(m0b + base + 4);
    ushort4 c0 = *(const ushort4*)(m1b + base);
    ushort4 c1 = *(const ushort4*)(m1b + base + 4);
    ushort4 rb0 = *(const ushort4*)(resb + base);
    ushort4 rb1 = *(const ushort4*)(resb + base + 4);
    float v[8] = { b2f(a0.x)+b2f(c0.x)+b2f(rb0.x), b2f(a0.y)+b2f(c0.y)+b2f(rb0.y),
                   b2f(a0.z)+b2f(c0.z)+b2f(rb0.z), b2f(a0.w)+b2f(c0.w)+b2f(rb0.w),
                   b2f(a1.x)+b2f(c1.x)+b2f(rb1.x), b2f(a1.y)+b2f(c1.y)+b2f(rb1.y),
                   b2f(a1.z)+b2f(c1.z)+b2f(rb1.z), b2f(a1.w)+b2f(c1.w)+b2f(rb1.w) };
    float s = 0.f, s2 = 0.f;
    #pragma unroll
    for (int i = 0; i < 8; i++) { s += v[i]; s2 += v[i]*v[i]; }
    #pragma unroll
    for (int d = 32; d >= 1; d >>= 1) { s += __shfl_xor(s, d); s2 += __shfl_xor(s2, d); }
    float mean = s * (1.0f / DIM);
    float rstd = rsqrtf(s2 * (1.0f / DIM) - mean*mean + 1e-5f);

    float4 g0 = *(const float4*)(g + lane*8);
    float4 g1 = *(const float4*)(g + lane*8 + 4);
    float4 b0 = *(const float4*)(be + lane*8);
    float4 b1 = *(const float4*)(be + lane*8 + 4);
    float gg[8] = {g0.x,g0.y,g0.z,g0.w,g1.x,g1.y,g1.z,g1.w};
    float bb[8] = {b0.x,b0.y,b0.z,b0.w,b1.x,b1.y,b1.z,b1.w};
    float o[8];
    #pragma unroll
    for (int i = 0; i < 8; i++) o[i] = (v[i] - mean)*rstd*gg[i] + bb[i];
    *(float4*)(outf + base)     = (float4){o[0],o[1],o[2],o[3]};
    *(float4*)(outf + base + 4) = (float4){o[4],o[5],o[6],o[7]};
}

extern "C" void kernel_launch(void* const* d_in, const int* in_sizes, int n_in,
                              void* d_out, int out_size, void* d_ws, size_t ws_size,
                              hipStream_t stream) {
    const float* x   = (const float*)d_in[0];
    const float* wq  = (const float*)d_in[1];
    const float* bq  = (const float*)d_in[2];
    const float* wk  = (const float*)d_in[3];
    const float* bk  = (const float*)d_in[4];
    const float* wv  = (const float*)d_in[5];
    const float* bv  = (const float*)d_in[6];
    const float* wo  = (const float*)d_in[7];
    const float* bo  = (const float*)d_in[8];
    const float* w1  = (const float*)d_in[9];
    const float* b1  = (const float*)d_in[10];
    const float* w2  = (const float*)d_in[11];
    const float* b2  = (const float*)d_in[12];
    const float* g1  = (const float*)d_in[13];
    const float* be1 = (const float*)d_in[14];
    const float* g2  = (const float*)d_in[15];
    const float* be2 = (const float*)d_in[16];
    float* out = (float*)d_out;

    char* w = (char*)d_ws;
    size_t off = 0;
    auto alloc = [&](size_t bytes){ void* p = w + off; off += (bytes + 255) & ~(size_t)255; return p; };
    unsigned short* xb     = (unsigned short*)alloc((size_t)MTOK*DIM*2);
    unsigned short* wqkvT  = (unsigned short*)alloc((size_t)1536*512*2);
    unsigned short* woT    = (unsigned short*)alloc((size_t)512*512*2);
    unsigned short* w1T    = (unsigned short*)alloc((size_t)2048*512*2);
    unsigned short* w2T    = (unsigned short*)alloc((size_t)512*2048*2);
    float*          bqkv   = (float*)alloc(1536*4);
    unsigned short* qb_    = (unsigned short*)alloc((size_t)32*SEQ*64*2);
    unsigned short* kb_    = (unsigned short*)alloc((size_t)32*SEQ*64*2);
    unsigned short* vT_    = (unsigned short*)alloc((size_t)32*64*SEQ*2);
    unsigned short* attno  = (unsigned short*)alloc((size_t)MTOK*DIM*2);
    unsigned short* x1b    = (unsigned short*)alloc((size_t)MTOK*DIM*2);
    unsigned short* h_     = (unsigned short*)alloc((size_t)MTOK*FFN_DIM*2);
    unsigned short* ffb    = (unsigned short*)alloc((size_t)2*MTOK*DIM*2);   // bf16 split-K partials

    // fused prep (1 launch): cvt_x | wqkv | wo | w1 | w2 | bias
    prep_kernel<<<7174, 256, 0, stream>>>(x, wq, wk, wv, wo, w1, w2, bq, bk, bv,
                                          xb, wqkvT, woT, w1T, w2T, bqkv);

    // QKV (fused): [8192,512] x [512,1536], 128x128
    gemm_bf16<1,1><<<dim3(64,12), 256, 0, stream>>>(xb, wqkvT, bqkv, nullptr,
                                                    qb_, kb_, vT_, MTOK, 1536, DIM);
    // attention (R7 config: 128 q/block, 4 waves)
    attn_mfma<<<dim3(16,32), 256, 0, stream>>>(qb_, kb_, vT_, attno);
    // O-proj -> 2 bf16 partials (128x128, split-K=2)
    gemm_bf16<0,2><<<dim3(64,4,2), 256, 0, stream>>>(attno, woT, bo, ffb,
                                                     nullptr, nullptr, nullptr, MTOK, DIM, DIM);
    // LN1(ff0+ff1+x) -> bf16
    ln1_kernel<<<MTOK/4, 256, 0, stream>>>(ffb, ffb + (size_t)MTOK*DIM, x, g1, be1, x1b);
    // FFN1 + fast GELU -> bf16 h (128x128, grid 1024 -> 4 blocks/CU)
    gemm_bf16<2,1><<<dim3(64,16), 256, 0, stream>>>(x1b, w1T, b1, h_,
                                                    nullptr, nullptr, nullptr, MTOK, FFN_DIM, DIM);
    // FFN2 -> 2 bf16 partials (128x128, split-K=2)
    gemm_bf16<0,2><<<dim3(64,4,2), 256, 0, stream>>>(h_, w2T, b2, ffb,
                                                     nullptr, nullptr, nullptr, MTOK, DIM, FFN_DIM);
    // LN2(ff0+ff1+x1b) -> out (fp32)
    ln2_kernel<<<MTOK/4, 256, 0, stream>>>(ffb, ffb + (size_t)MTOK*DIM, x1b, g2, be2, out);
}